// Round 2
// baseline (1948.760 us; speedup 1.0000x reference)
//
#include <hip/hip_runtime.h>
#include <hip/hip_bf16.h>

#define N_NODES 200000
#define N_EDGES 200000
#define IN_C 512
#define HID_C 512
#define OUT_C 256
#define K_HOPS 10

typedef __hip_bfloat16 bf16;
typedef __attribute__((ext_vector_type(8))) short short8;
typedef __attribute__((ext_vector_type(4))) float floatx4;

__device__ __forceinline__ void async_copy16(const void* g, void* l) {
  __builtin_amdgcn_global_load_lds(
      (const __attribute__((address_space(1))) void*)g,
      (__attribute__((address_space(3))) void*)l, 16, 0, 0);
}

__device__ __forceinline__ float bf2f(unsigned short u) {
  unsigned int x = ((unsigned int)u) << 16;
  return __builtin_bit_cast(float, x);
}
__device__ __forceinline__ unsigned short f2bf(float f) {
  return __builtin_bit_cast(unsigned short, __float2bfloat16(f));
}

// ---- f32 -> bf16 cast (contiguous), 4 elems/thread ----
__global__ void cast_kernel(const float* __restrict__ in, unsigned short* __restrict__ out,
                            int n) {
  int i = (blockIdx.x * 256 + threadIdx.x) * 4;
  if (i < n) {
    float4 v = *(const float4*)(in + i);
    ushort4 p;
    p.x = f2bf(v.x); p.y = f2bf(v.y); p.z = f2bf(v.z); p.w = f2bf(v.w);
    *(ushort4*)(out + i) = p;
  }
}

// ---- W [K,N] f32 row-major -> WT [N,K] bf16 row-major ----
__global__ void transpose_cast_kernel(const float* __restrict__ W, bf16* __restrict__ WT,
                                      int Kd, int Nd) {
  int idx = blockIdx.x * 256 + threadIdx.x;
  if (idx < Kd * Nd) {
    int k = idx / Nd, n = idx - k * Nd;
    WT[(size_t)n * Kd + k] = __float2bfloat16(W[idx]);
  }
}

__global__ void deg_kernel(const int* __restrict__ rowIdx, float* __restrict__ deg, int E) {
  int e = blockIdx.x * 256 + threadIdx.x;
  if (e < E) atomicAdd(&deg[rowIdx[e]], 1.0f);
}

__global__ void coef_kernel(const int* __restrict__ rowIdx, const int* __restrict__ colIdx,
                            const float* __restrict__ deg, float* __restrict__ coef, int E) {
  int e = blockIdx.x * 256 + threadIdx.x;
  if (e < E) {
    float dr = deg[rowIdx[e]];
    float dc = deg[colIdx[e]];
    float a = dr > 0.f ? rsqrtf(dr) : 0.f;
    float b = dc > 0.f ? rsqrtf(dc) : 0.f;
    coef[e] = a * b;
  }
}

// C = A * BT^T (+bias), A [M,K] bf16 row-major, BT [N,K] bf16 row-major, bias f32.
// EPI 0: relu -> bf16 Cb.   EPI 1: bf16 Cb (no relu) AND f32 Cacc = gamma[0]*v.
template <int EPI>
__global__ __launch_bounds__(256)
void gemm_bt_kernel(const bf16* __restrict__ A, const bf16* __restrict__ BT,
                    const float* __restrict__ bias, int M, int N, int K,
                    bf16* __restrict__ Cb, float* __restrict__ Cacc,
                    const float* __restrict__ gamma) {
  __shared__ bf16 As[128 * 32];
  __shared__ bf16 Bs[128 * 32];

  const int tid = threadIdx.x;
  const int lane = tid & 63;
  const int wave = tid >> 6;
  const int m0 = blockIdx.x * 128;
  const int n0 = blockIdx.y * 128;

  floatx4 zero = {0.f, 0.f, 0.f, 0.f};
  floatx4 acc[4][4];
#pragma unroll
  for (int i = 0; i < 4; ++i)
#pragma unroll
    for (int j = 0; j < 4; ++j) acc[i][j] = zero;

  const int wm = (wave & 1) * 64;   // wave's 64x64 sub-tile
  const int wn = (wave >> 1) * 64;
  const int lrow = lane & 15;
  const int kgrp = lane >> 4;       // 0..3 -> which 8-elem k-chunk

  int ar0 = m0 + (tid >> 2);
  int ar1 = ar0 + 64;
  ar0 = ar0 < M ? ar0 : M - 1;      // clamp OOB rows (dup load; store is guarded)
  ar1 = ar1 < M ? ar1 : M - 1;
  const int kc = (tid & 3) * 8;

  const bf16* Ag0 = A + (size_t)ar0 * K + kc;
  const bf16* Ag1 = A + (size_t)ar1 * K + kc;
  const bf16* Bg0 = BT + (size_t)(n0 + (tid >> 2)) * K + kc;
  const bf16* Bg1 = BT + (size_t)(n0 + 64 + (tid >> 2)) * K + kc;

  bf16* Al0 = &As[tid * 8];
  bf16* Al1 = &As[tid * 8 + 2048];
  bf16* Bl0 = &Bs[tid * 8];
  bf16* Bl1 = &Bs[tid * 8 + 2048];

  for (int k0 = 0; k0 < K; k0 += 32) {
    async_copy16(Ag0 + k0, Al0);
    async_copy16(Ag1 + k0, Al1);
    async_copy16(Bg0 + k0, Bl0);
    async_copy16(Bg1 + k0, Bl1);
    __syncthreads();  // compiler emits vmcnt(0) drain before barrier
    short8 a[4], b[4];
#pragma unroll
    for (int i = 0; i < 4; ++i) {
      a[i] = *(const short8*)&As[(wm + i * 16 + lrow) * 32 + kgrp * 8];
      b[i] = *(const short8*)&Bs[(wn + i * 16 + lrow) * 32 + kgrp * 8];
    }
#pragma unroll
    for (int i = 0; i < 4; ++i)
#pragma unroll
      for (int j = 0; j < 4; ++j)
        acc[i][j] = __builtin_amdgcn_mfma_f32_16x16x32_bf16(a[i], b[j], acc[i][j], 0, 0, 0);
    __syncthreads();
  }

  // C/D layout: col = lane&15, row = (lane>>4)*4 + r   [m89-verified]
  const int crow = (lane >> 4) * 4;
  const int ccol = lane & 15;
  float g0 = 0.f;
  if (EPI == 1) g0 = gamma[0];
  float bcol[4];
#pragma unroll
  for (int j = 0; j < 4; ++j) bcol[j] = bias[n0 + wn + j * 16 + ccol];

#pragma unroll
  for (int i = 0; i < 4; ++i) {
#pragma unroll
    for (int r = 0; r < 4; ++r) {
      const int gr = m0 + wm + i * 16 + crow + r;
      if (gr < M) {
#pragma unroll
        for (int j = 0; j < 4; ++j) {
          const int gc = n0 + wn + j * 16 + ccol;
          float v = acc[i][j][r] + bcol[j];
          if (EPI == 0) {
            Cb[(size_t)gr * N + gc] = __float2bfloat16(fmaxf(v, 0.f));
          } else {
            Cb[(size_t)gr * N + gc] = __float2bfloat16(v);
            Cacc[(size_t)gr * N + gc] = g0 * v;
          }
        }
      }
    }
  }
}

// one wave per row e; 64 lanes x 4 channels (bf16 x-buffers, f32 accumulator)
// LAST=0: write xnew, oacc += g*v.   LAST=1: out = oacc + g*v (f32), no xnew.
template <int LAST>
__global__ void hop_kernel(const unsigned short* __restrict__ xold,
                           unsigned short* __restrict__ xnew,
                           float* __restrict__ oacc, float* __restrict__ outp,
                           const int* __restrict__ colIdx, const float* __restrict__ coef,
                           const float* __restrict__ gamma, int k) {
  int gtid = blockIdx.x * 256 + threadIdx.x;
  int e = __builtin_amdgcn_readfirstlane(gtid >> 6);  // wave-uniform -> scalar loads
  int c = (gtid & 63) * 4;
  int src = colIdx[e];
  float cf = coef[e];
  float g = gamma[k];
  ushort4 pv = *(const ushort4*)(xold + (size_t)src * 256 + c);
  float4 v;
  v.x = fmaxf(bf2f(pv.x) * cf, 0.f);
  v.y = fmaxf(bf2f(pv.y) * cf, 0.f);
  v.z = fmaxf(bf2f(pv.z) * cf, 0.f);
  v.w = fmaxf(bf2f(pv.w) * cf, 0.f);
  if (LAST == 0) {
    ushort4 pw;
    pw.x = f2bf(v.x); pw.y = f2bf(v.y); pw.z = f2bf(v.z); pw.w = f2bf(v.w);
    *(ushort4*)(xnew + (size_t)e * 256 + c) = pw;
    float4* oa = (float4*)(oacc + (size_t)e * 256 + c);
    float4 o = *oa;
    o.x += g * v.x; o.y += g * v.y; o.z += g * v.z; o.w += g * v.w;
    *oa = o;
  } else {
    const float4* oa = (const float4*)(oacc + (size_t)e * 256 + c);
    float4 o = *oa;
    o.x += g * v.x; o.y += g * v.y; o.z += g * v.z; o.w += g * v.w;
    *(float4*)(outp + (size_t)e * 256 + c) = o;
  }
}

extern "C" void kernel_launch(void* const* d_in, const int* in_sizes, int n_in,
                              void* d_out, int out_size, void* d_ws, size_t ws_size,
                              hipStream_t stream) {
  const float* x = (const float*)d_in[0];     // [N, 512] f32
  const int* edge = (const int*)d_in[1];      // [2,E] int32: row=edge[0:E), col=edge[E:2E)
  const float* W1 = (const float*)d_in[2];    // [512, 512] f32
  const float* b1 = (const float*)d_in[3];    // [512] f32
  const float* W2 = (const float*)d_in[4];    // [512, 256] f32
  const float* b2 = (const float*)d_in[5];    // [256] f32
  const float* gamma = (const float*)d_in[6]; // [11] f32
  float* out = (float*)d_out;                 // [N, 256] f32

  // workspace layout (bytes), total ~617 MB:
  //  region A [0, 204.8MB): xb16 (bf16 cast of x) during GEMM1;
  //                         reused as xb0/xb1 bf16 hop ping-pong afterwards.
  char* ws = (char*)d_ws;
  unsigned short* xb16 = (unsigned short*)ws;              // N*512*2 = 204,800,000
  unsigned short* xb0 = (unsigned short*)ws;               // N*256*2 = 102,400,000
  unsigned short* xb1 = (unsigned short*)(ws + 102400000); // N*256*2
  bf16* h1 = (bf16*)(ws + 204800000);                      // N*512*2 = 204,800,000
  float* oacc = (float*)(ws + 409600000);                  // N*256*4 = 204,800,000
  bf16* W1T = (bf16*)(ws + 614400000);                     // 512*512*2 = 524,288
  bf16* W2T = (bf16*)(ws + 614924288);                     // 256*512*2 = 262,144
  float* deg = (float*)(ws + 615186432);                   // N*4 = 800,000
  float* coef = (float*)(ws + 615986432);                  // E*4 = 800,000

  const int* rowIdx = edge;
  const int* colIdx = edge + N_EDGES;

  hipMemsetAsync(deg, 0, N_NODES * sizeof(float), stream);

  cast_kernel<<<dim3(N_NODES * IN_C / 4 / 256), 256, 0, stream>>>(x, xb16, N_NODES * IN_C);
  transpose_cast_kernel<<<dim3(IN_C * HID_C / 256), 256, 0, stream>>>(W1, W1T, IN_C, HID_C);
  transpose_cast_kernel<<<dim3(HID_C * OUT_C / 256), 256, 0, stream>>>(W2, W2T, HID_C, OUT_C);

  deg_kernel<<<dim3((N_EDGES + 255) / 256), 256, 0, stream>>>(rowIdx, deg, N_EDGES);
  coef_kernel<<<dim3((N_EDGES + 255) / 256), 256, 0, stream>>>(rowIdx, colIdx, deg, coef, N_EDGES);

  // h1 = relu(x @ W1 + b1) [N,512] bf16
  gemm_bt_kernel<0><<<dim3((N_NODES + 127) / 128, HID_C / 128), 256, 0, stream>>>(
      (const bf16*)xb16, W1T, b1, N_NODES, HID_C, IN_C, h1, nullptr, nullptr);
  // h = h1 @ W2 + b2 -> xb0 (bf16, no relu); oacc = gamma[0]*h (f32)
  gemm_bt_kernel<1><<<dim3((N_NODES + 127) / 128, OUT_C / 128), 256, 0, stream>>>(
      h1, W2T, b2, N_NODES, OUT_C, HID_C, (bf16*)xb0, oacc, gamma);

  unsigned short* cur = xb0;
  unsigned short* nxt = xb1;
  for (int k = 1; k < K_HOPS; ++k) {
    hop_kernel<0><<<dim3(N_NODES * 64 / 256), 256, 0, stream>>>(
        cur, nxt, oacc, nullptr, colIdx, coef, gamma, k);
    unsigned short* t = cur; cur = nxt; nxt = t;
  }
  hop_kernel<1><<<dim3(N_NODES * 64 / 256), 256, 0, stream>>>(
      cur, nullptr, oacc, out, colIdx, coef, gamma, K_HOPS);
}